// Round 8
// baseline (108.164 us; speedup 1.0000x reference)
//
#include <hip/hip_runtime.h>
#include <stdint.h>

// GPT2 attention fused pipeline, MI355X/gfx950.
// B=2, S=2048, H=768, nh=12, hd=64. fp32 I/O, bf16 internal compute (MFMA).

#define B_   2
#define S_   2048
#define H_   768
#define NH_  12
#define HD_  64
#define M_   4096      // B_*S_
#define K_   768
#define N_QKV 2304
#define QKV_ELEMS (B_*NH_*S_*HD_)   // per tensor (Q or K or V^T)
#define INF_ __builtin_inff()
#define SCL_ 0.18033688f            // (1/sqrt(64)) * log2(e)

using bf16x8 = __attribute__((ext_vector_type(8))) __bf16;
using f32x4  = __attribute__((ext_vector_type(4))) float;
using f32x16 = __attribute__((ext_vector_type(16))) float;

__device__ inline unsigned short f2bf(float f) {
  unsigned int u = __float_as_uint(f);
  u = (u + 0x7FFFu + ((u >> 16) & 1u)) >> 16;   // RNE
  return (unsigned short)u;
}
__device__ inline float fexp2(float x) {        // v_exp_f32 = 2^x
  float r; asm("v_exp_f32 %0, %1" : "=v"(r) : "v"(x)); return r;
}
__device__ inline unsigned cvtpk(float lo, float hi) {
  unsigned r; asm("v_cvt_pk_bf16_f32 %0, %1, %2" : "=v"(r) : "v"(lo), "v"(hi)); return r;
}
// async global->LDS, 16B per lane; lds base must be wave-uniform.
__device__ inline void gload_lds16(const void* g, void* l) {
  __builtin_amdgcn_global_load_lds((const __attribute__((address_space(1))) void*)g,
                                   (__attribute__((address_space(3))) void*)l, 16, 0, 0);
}

// ---------------- cast fp32 -> bf16 (3 tensors in one launch) ----------------
__global__ void cast3(const float* __restrict__ s0, unsigned short* __restrict__ d0, int n0f,
                      const float* __restrict__ s1, unsigned short* __restrict__ d1, int n1f,
                      const float* __restrict__ s2, unsigned short* __restrict__ d2, int n2f) {
  int i = blockIdx.x * blockDim.x + threadIdx.x;
  const float* s; unsigned short* d; int j;
  if (i < n0f)                { s = s0; d = d0; j = i; }
  else if (i < n0f + n1f)     { s = s1; d = d1; j = i - n0f; }
  else if (i < n0f + n1f + n2f) { s = s2; d = d2; j = i - n0f - n1f; }
  else return;
  float4 v = reinterpret_cast<const float4*>(s)[j];
  ushort4 o;
  o.x = f2bf(v.x); o.y = f2bf(v.y); o.z = f2bf(v.z); o.w = f2bf(v.w);
  reinterpret_cast<ushort4*>(d)[j] = o;
}

// ---------------- NT GEMM: C[m,n] = sum_k A[m,k]*Bw[n,k] + bias[n] ----------------
// Staging via global_load_lds (16B/lane, linear LDS both sides).
// MODE 0: scatter bf16 into Q (b,h,s,d), K (b,h,s,d), V^T (b,h,d,s).
// MODE 1: fp32 store to out.
template<int N, int MODE>
__global__ __launch_bounds__(256, 2)
void gemm_nt(const unsigned short* __restrict__ A,
             const unsigned short* __restrict__ Bw,
             const float* __restrict__ bias,
             unsigned short* __restrict__ qkv_base,
             float* __restrict__ outp)
{
  __shared__ unsigned short As[128*32];
  __shared__ unsigned short Bs[128*32];
  const int tid  = threadIdx.x;
  const int lane = tid & 63;
  const int wid  = tid >> 6;
  const int g = lane >> 4, lr = lane & 15;
  const int wm = wid >> 1, wn = wid & 1;
  const int n0 = blockIdx.x * 128;
  const int m0 = blockIdx.y * 128;

  f32x4 acc[4][4];
  #pragma unroll
  for (int i = 0; i < 4; ++i)
    #pragma unroll
    for (int j = 0; j < 4; ++j) acc[i][j] = f32x4{0.f, 0.f, 0.f, 0.f};

  for (int k0 = 0; k0 < K_; k0 += 32) {
    // stage A,B tiles: chunk c (0..511) of 8 bf16; row=c>>2, seg=c&3; LDS linear c*16B
    #pragma unroll
    for (int it = 0; it < 2; ++it) {
      int c = it*256 + wid*64 + lane;
      int row = c >> 2, seg = c & 3;
      int lb = __builtin_amdgcn_readfirstlane((it*256 + wid*64) * 8);  // ushort offset
      gload_lds16(&A [(size_t)(m0 + row) * K_ + k0 + seg*8], &As[lb]);
      gload_lds16(&Bw[(size_t)(n0 + row) * K_ + k0 + seg*8], &Bs[lb]);
    }
    __syncthreads();
    bf16x8 af[4], bfr[4];
    #pragma unroll
    for (int i = 0; i < 4; ++i) {
      int ra = wm*64 + i*16 + lr;
      af[i]  = *reinterpret_cast<const bf16x8*>(&As[ra*32 + g*8]);
      int rb = wn*64 + i*16 + lr;
      bfr[i] = *reinterpret_cast<const bf16x8*>(&Bs[rb*32 + g*8]);
    }
    #pragma unroll
    for (int i = 0; i < 4; ++i)
      #pragma unroll
      for (int j = 0; j < 4; ++j)
        acc[i][j] = __builtin_amdgcn_mfma_f32_16x16x32_bf16(af[i], bfr[j], acc[i][j], 0, 0, 0);
    __syncthreads();
  }

  // epilogue: C row = m0+wm*64+i*16+g*4+r, col = n0+wn*64+j*16+lr  (m89 layout)
  #pragma unroll
  for (int j = 0; j < 4; ++j) {
    int col = n0 + wn*64 + j*16 + lr;
    float bv = bias[col];
    if constexpr (MODE == 0) {
      int which = col / 768;               // 0=Q 1=K 2=V (frag never crosses boundary)
      int rem = col - which * 768;
      int h = rem >> 6, d = rem & 63;
      if (which < 2) {
        unsigned short* dst = qkv_base + (size_t)which * QKV_ELEMS;
        #pragma unroll
        for (int i = 0; i < 4; ++i)
          #pragma unroll
          for (int r = 0; r < 4; ++r) {
            int rowm = m0 + wm*64 + i*16 + g*4 + r;
            int bb = rowm >> 11, ss = rowm & 2047;
            dst[(((size_t)(bb*NH_ + h))*S_ + ss)*HD_ + d] = f2bf(acc[i][j][r] + bv);
          }
      } else {
        // V stored TRANSPOSED per head: (b,h,d,s); 4 consecutive s -> 8B store
        unsigned short* dst = qkv_base + 2*(size_t)QKV_ELEMS;
        #pragma unroll
        for (int i = 0; i < 4; ++i) {
          int rowm = m0 + wm*64 + i*16 + g*4;
          int bb = rowm >> 11, ss = rowm & 2047;
          unsigned w0 = (unsigned)f2bf(acc[i][j][0] + bv) | ((unsigned)f2bf(acc[i][j][1] + bv) << 16);
          unsigned w1 = (unsigned)f2bf(acc[i][j][2] + bv) | ((unsigned)f2bf(acc[i][j][3] + bv) << 16);
          uint2 u; u.x = w0; u.y = w1;
          *reinterpret_cast<uint2*>(&dst[(((size_t)(bb*NH_ + h))*HD_ + d)*S_ + ss]) = u;
        }
      }
    } else {
      #pragma unroll
      for (int i = 0; i < 4; ++i)
        #pragma unroll
        for (int r = 0; r < 4; ++r) {
          int rowm = m0 + wm*64 + i*16 + g*4 + r;
          outp[(size_t)rowm * H_ + col] = acc[i][j][r] + bv;
        }
    }
  }
}

// ---------------- flash attention (causal), barrier-free streaming ----------------
// Block = 4 waves; processes the PAIRED q-tiles (63-pr, pr) -> uniform duration;
// grid 768 = exactly 3 blocks/CU at launch_bounds(256,3), all resident.
// Wave w handles kv tiles t === w (mod 4) with private (m,l,O^T); 4-way LDS merge.
// Loop 2x-unrolled, disjoint register sets; sched_barrier(0) PINS the prefetch
// load clusters so the compiler cannot sink them to their uses.
// Cross-half softmax reduce via __shfl_xor(.,32) (R4-R6 proven; the R7 permlane
// half-swap single-output idiom was WRONG -> NaN).
__global__ __launch_bounds__(256, 3)
void attn_fwd(const unsigned short* __restrict__ Qp,
              const unsigned short* __restrict__ Kp,
              const unsigned short* __restrict__ Vtp,
              unsigned short* __restrict__ attn)
{
  __shared__ float Osc[4][32*36];     // [wave][q*36 + d-half]
  __shared__ float mlb[4][64];        // [wave][{m[32], l[32]}]

  const int tid = threadIdx.x;
  const int l = tid & 63, w = tid >> 6;
  const int q31 = l & 31, hi = l >> 5;
  // XCD-locked decode: idx%8 == bh%8 (3 heads per XCD -> Q+K+V^T 2.25MB, L2-fits).
  const int idx = blockIdx.x;
  const int bh = (idx & 7) + 8 * ((idx >> 3) % 3);
  const int pr = (idx >> 3) / 3;       // 0..31
  const unsigned short* Qh  = Qp  + (size_t)bh * S_ * HD_;
  const unsigned short* Kh  = Kp  + (size_t)bh * S_ * HD_;
  const unsigned short* Vth = Vtp + (size_t)bh * HD_ * S_;
  const int bb = bh / NH_, hh = bh % NH_;

  for (int qi = 0; qi < 2; ++qi) {
    const int qt = qi ? pr : (63 - pr);
    const int qrow = qt*32 + q31;

    // Q B-frags (col = q31, k = d)
    bf16x8 qf[4];
    #pragma unroll
    for (int ks = 0; ks < 4; ++ks)
      qf[ks] = *reinterpret_cast<const bf16x8*>(&Qh[(size_t)qrow*HD_ + ks*16 + hi*8]);

    f32x16 oacc0, oacc1;
    #pragma unroll
    for (int r = 0; r < 16; ++r) { oacc0[r] = 0.f; oacc1[r] = 0.f; }
    float mrun = -INF_, lrun = 0.f;

    const int p = w;                                   // kv-tile residue (mod 4)
    const int nt = (qt >= p) ? ((qt - p) >> 2) + 1 : 0;
    const bool dw = ((qt & 3) == p);                   // this wave owns the diag tile
    const int ntm1 = nt - 1;

    const unsigned short* kptr  = Kh  + (size_t)(p*32 + q31)*HD_ + hi*8;
    const unsigned short* vptr0 = Vth + (size_t)q31*S_      + p*32 + hi*8;
    const unsigned short* vptr1 = Vth + (size_t)(32+q31)*S_ + p*32 + hi*8;

    uint4 ka0, ka1, ka2, ka3, kc0, kc1, kc2, kc3;
    uint4 va0, va1, va2, va3, vc0, vc1, vc2, vc3;

    auto LOADK_A = [&]() {
      ka0 = *reinterpret_cast<const uint4*>(kptr);
      ka1 = *reinterpret_cast<const uint4*>(kptr + 16);
      ka2 = *reinterpret_cast<const uint4*>(kptr + 32);
      ka3 = *reinterpret_cast<const uint4*>(kptr + 48);
      kptr += 128*HD_;
    };
    auto LOADK_B = [&]() {
      kc0 = *reinterpret_cast<const uint4*>(kptr);
      kc1 = *reinterpret_cast<const uint4*>(kptr + 16);
      kc2 = *reinterpret_cast<const uint4*>(kptr + 32);
      kc3 = *reinterpret_cast<const uint4*>(kptr + 48);
      kptr += 128*HD_;
    };
    auto LOADV_A = [&]() {
      va0 = *reinterpret_cast<const uint4*>(vptr0);
      va1 = *reinterpret_cast<const uint4*>(vptr0 + 16);
      va2 = *reinterpret_cast<const uint4*>(vptr1);
      va3 = *reinterpret_cast<const uint4*>(vptr1 + 16);
      vptr0 += 128; vptr1 += 128;
    };
    auto LOADV_B = [&]() {
      vc0 = *reinterpret_cast<const uint4*>(vptr0);
      vc1 = *reinterpret_cast<const uint4*>(vptr0 + 16);
      vc2 = *reinterpret_cast<const uint4*>(vptr1);
      vc3 = *reinterpret_cast<const uint4*>(vptr1 + 16);
      vptr0 += 128; vptr1 += 128;
    };

    auto STEP = [&](uint4& k0, uint4& k1, uint4& k2, uint4& k3,
                    uint4& v0, uint4& v1, uint4& v2, uint4& v3, bool isDiag) {
      // ---- S^T = K . Q^T (32 kv x 32 q) ----
      f32x16 sf;
      #pragma unroll
      for (int r = 0; r < 16; ++r) sf[r] = 0.f;
      __builtin_amdgcn_s_setprio(1);
      sf = __builtin_amdgcn_mfma_f32_32x32x16_bf16(*reinterpret_cast<bf16x8*>(&k0), qf[0], sf, 0, 0, 0);
      sf = __builtin_amdgcn_mfma_f32_32x32x16_bf16(*reinterpret_cast<bf16x8*>(&k1), qf[1], sf, 0, 0, 0);
      sf = __builtin_amdgcn_mfma_f32_32x32x16_bf16(*reinterpret_cast<bf16x8*>(&k2), qf[2], sf, 0, 0, 0);
      sf = __builtin_amdgcn_mfma_f32_32x32x16_bf16(*reinterpret_cast<bf16x8*>(&k3), qf[3], sf, 0, 0, 0);
      __builtin_amdgcn_s_setprio(0);

      if (isDiag) {
        const int kv0 = qt*32;
        #pragma unroll
        for (int r = 0; r < 16; ++r) {
          int kv = kv0 + (r & 3) + 8*(r >> 2) + 4*hi;
          if (kv > qrow) sf[r] = -1e38f;
        }
      }

      // ---- lane-local online softmax (exp2 domain), defer-max (THR=8) ----
      // balanced max tree (fmaxf nests fuse to v_max3)
      float x0 = fmaxf(fmaxf(sf[0],  sf[1]),  fmaxf(sf[2],  sf[3]));
      float x1 = fmaxf(fmaxf(sf[4],  sf[5]),  fmaxf(sf[6],  sf[7]));
      float x2 = fmaxf(fmaxf(sf[8],  sf[9]),  fmaxf(sf[10], sf[11]));
      float x3 = fmaxf(fmaxf(sf[12], sf[13]), fmaxf(sf[14], sf[15]));
      float mtr = fmaxf(fmaxf(x0, x1), fmaxf(x2, x3));
      mtr = fmaxf(mtr, __shfl_xor(mtr, 32));        // cross-half (proven path)
      float mt = mtr * SCL_;
      float corr = 1.f;
      if (__any(mt > mrun + 8.0f)) {
        float mnew = fmaxf(mrun, mt);
        corr = fexp2(mrun - mnew);
        mrun = mnew;
        #pragma unroll
        for (int r = 0; r < 16; ++r) { oacc0[r] *= corr; oacc1[r] *= corr; }
      }
      #pragma unroll
      for (int r = 0; r < 16; ++r)
        sf[r] = fexp2(fmaf(sf[r], SCL_, -mrun));
      // balanced sum tree
      float s0 = (sf[0]  + sf[1])  + (sf[2]  + sf[3]);
      float s1 = (sf[4]  + sf[5])  + (sf[6]  + sf[7]);
      float s2 = (sf[8]  + sf[9])  + (sf[10] + sf[11]);
      float s3 = (sf[12] + sf[13]) + (sf[14] + sf[15]);
      float rs = (s0 + s1) + (s2 + s3);
      rs += __shfl_xor(rs, 32);                     // cross-half (proven path)
      lrun = fmaf(lrun, corr, rs);

      // ---- P^T B-frags in-register: cvt_pk pairs + permlane32_swap ----
      unsigned pw0 = cvtpk(sf[0],  sf[1]);
      unsigned pw1 = cvtpk(sf[2],  sf[3]);
      unsigned pw2 = cvtpk(sf[4],  sf[5]);
      unsigned pw3 = cvtpk(sf[6],  sf[7]);
      unsigned pw4 = cvtpk(sf[8],  sf[9]);
      unsigned pw5 = cvtpk(sf[10], sf[11]);
      unsigned pw6 = cvtpk(sf[12], sf[13]);
      unsigned pw7 = cvtpk(sf[14], sf[15]);
      asm("v_permlane32_swap_b32 %0, %1" : "+v"(pw0), "+v"(pw2));
      asm("v_permlane32_swap_b32 %0, %1" : "+v"(pw1), "+v"(pw3));
      asm("v_permlane32_swap_b32 %0, %1" : "+v"(pw4), "+v"(pw6));
      asm("v_permlane32_swap_b32 %0, %1" : "+v"(pw5), "+v"(pw7));
      uint4 pf0; pf0.x = pw0; pf0.y = pw1; pf0.z = pw2; pf0.w = pw3;
      uint4 pf1; pf1.x = pw4; pf1.y = pw5; pf1.z = pw6; pf1.w = pw7;

      // ---- O^T += V^T . P^T ----
      __builtin_amdgcn_s_setprio(1);
      oacc0 = __builtin_amdgcn_mfma_f32_32x32x16_bf16(
          *reinterpret_cast<bf16x8*>(&v0), *reinterpret_cast<bf16x8*>(&pf0), oacc0, 0, 0, 0);
      oacc0 = __builtin_amdgcn_mfma_f32_32x32x16_bf16(
          *reinterpret_cast<bf16x8*>(&v1), *reinterpret_cast<bf16x8*>(&pf1), oacc0, 0, 0, 0);
      oacc1 = __builtin_amdgcn_mfma_f32_32x32x16_bf16(
          *reinterpret_cast<bf16x8*>(&v2), *reinterpret_cast<bf16x8*>(&pf0), oacc1, 0, 0, 0);
      oacc1 = __builtin_amdgcn_mfma_f32_32x32x16_bf16(
          *reinterpret_cast<bf16x8*>(&v3), *reinterpret_cast<bf16x8*>(&pf1), oacc1, 0, 0, 0);
      __builtin_amdgcn_s_setprio(0);
    };

    // ---- 2x-unrolled pipelined main loop with PINNED prefetch ----
    if (nt > 0) LOADK_A();
    int i = 0;
    for (; i + 2 <= nt; i += 2) {
      LOADV_A();                                   // V(i)
      LOADK_B();                                   // K(i+1)
      __builtin_amdgcn_sched_barrier(0);           // pin loads above compute
      STEP(ka0, ka1, ka2, ka3, va0, va1, va2, va3, dw && (i == ntm1));
      LOADV_B();                                   // V(i+1)
      if (i + 2 < nt) LOADK_A();                   // K(i+2)
      __builtin_amdgcn_sched_barrier(0);           // pin loads above compute
      STEP(kc0, kc1, kc2, kc3, vc0, vc1, vc2, vc3, dw && (i + 1 == ntm1));
    }
    if (i < nt) {
      LOADV_A();
      __builtin_amdgcn_sched_barrier(0);
      STEP(ka0, ka1, ka2, ka3, va0, va1, va2, va3, dw && (i == ntm1));
    }

    // ---- 4-way merge in two d-half phases ----
    const int q = tid & 31, dseg8 = tid >> 5;
    __syncthreads();   // protect Osc against previous q-tile's readers

    // phase 0: d in [0,32)
    #pragma unroll
    for (int rr = 0; rr < 4; ++rr) {
      f32x4 a;
      #pragma unroll
      for (int e = 0; e < 4; ++e) a[e] = oacc0[4*rr + e];
      *reinterpret_cast<f32x4*>(&Osc[w][q31*36 + 8*rr + 4*hi]) = a;
    }
    if (hi == 0) { mlb[w][q31] = mrun; mlb[w][32 + q31] = lrun; }
    __syncthreads();

    float e0, e1, e2, e3, inv;
    {
      float m0 = mlb[0][q], m1 = mlb[1][q], m2 = mlb[2][q], m3 = mlb[3][q];
      float l0 = mlb[0][32+q], l1 = mlb[1][32+q], l2 = mlb[2][32+q], l3 = mlb[3][32+q];
      float M = fmaxf(fmaxf(m0, m1), fmaxf(m2, m3));
      e0 = fexp2(m0 - M); e1 = fexp2(m1 - M); e2 = fexp2(m2 - M); e3 = fexp2(m3 - M);
      inv = 1.f / (l0*e0 + l1*e1 + l2*e2 + l3*e3);
    }
    if (dseg8 < 4) {
      const int dd = dseg8*8;
      f32x4 a0 = *reinterpret_cast<f32x4*>(&Osc[0][q*36 + dd]);
      f32x4 b0 = *reinterpret_cast<f32x4*>(&Osc[0][q*36 + dd + 4]);
      f32x4 a1 = *reinterpret_cast<f32x4*>(&Osc[1][q*36 + dd]);
      f32x4 b1 = *reinterpret_cast<f32x4*>(&Osc[1][q*36 + dd + 4]);
      f32x4 a2 = *reinterpret_cast<f32x4*>(&Osc[2][q*36 + dd]);
      f32x4 b2 = *reinterpret_cast<f32x4*>(&Osc[2][q*36 + dd + 4]);
      f32x4 a3 = *reinterpret_cast<f32x4*>(&Osc[3][q*36 + dd]);
      f32x4 b3 = *reinterpret_cast<f32x4*>(&Osc[3][q*36 + dd + 4]);
      f32x4 ra, rb;
      #pragma unroll
      for (int e = 0; e < 4; ++e) {
        ra[e] = (a0[e]*e0 + a1[e]*e1 + a2[e]*e2 + a3[e]*e3) * inv;
        rb[e] = (b0[e]*e0 + b1[e]*e1 + b2[e]*e2 + b3[e]*e3) * inv;
      }
      uint4 ov;
      ov.x = cvtpk(ra[0], ra[1]); ov.y = cvtpk(ra[2], ra[3]);
      ov.z = cvtpk(rb[0], rb[1]); ov.w = cvtpk(rb[2], rb[3]);
      *reinterpret_cast<uint4*>(&attn[((size_t)(bb*S_ + qt*32 + q))*H_ + hh*HD_ + dd]) = ov;
    }
    __syncthreads();

    // phase 1: d in [32,64)
    #pragma unroll
    for (int rr = 0; rr < 4; ++rr) {
      f32x4 a;
      #pragma unroll
      for (int e = 0; e < 4; ++e) a[e] = oacc1[4*rr + e];
      *reinterpret_cast<f32x4*>(&Osc[w][q31*36 + 8*rr + 4*hi]) = a;
    }
    __syncthreads();

    if (dseg8 >= 4) {
      const int dd = (dseg8 - 4)*8;
      f32x4 a0 = *reinterpret_cast<f32x4*>(&Osc[0][q*36 + dd]);
      f32x4 b0 = *reinterpret_cast<f32x4*>(&Osc[0][q*36 + dd + 4]);
      f32x4 a1 = *reinterpret_cast<f32x4*>(&Osc[1][q*36 + dd]);
      f32x4 b1 = *reinterpret_cast<f32x4*>(&Osc[1][q*36 + dd + 4]);
      f32x4 a2 = *reinterpret_cast<f32x4*>(&Osc[2][q*36 + dd]);
      f32x4 b2 = *reinterpret_cast<f32x4*>(&Osc[2][q*36 + dd + 4]);
      f32x4 a3 = *reinterpret_cast<f32x4*>(&Osc[3][q*36 + dd]);
      f32x4 b3 = *reinterpret_cast<f32x4*>(&Osc[3][q*36 + dd + 4]);
      f32x4 ra, rb;
      #pragma unroll
      for (int e = 0; e < 4; ++e) {
        ra[e] = (a0[e]*e0 + a1[e]*e1 + a2[e]*e2 + a3[e]*e3) * inv;
        rb[e] = (b0[e]*e0 + b1[e]*e1 + b2[e]*e2 + b3[e]*e3) * inv;
      }
      uint4 ov;
      ov.x = cvtpk(ra[0], ra[1]); ov.y = cvtpk(ra[2], ra[3]);
      ov.z = cvtpk(rb[0], rb[1]); ov.w = cvtpk(rb[2], rb[3]);
      *reinterpret_cast<uint4*>(&attn[((size_t)(bb*S_ + qt*32 + q))*H_ + hh*HD_ + 32 + dd]) = ov;
    }
    __syncthreads();
  }
}

// ---------------- launch ----------------
extern "C" void kernel_launch(void* const* d_in, const int* in_sizes, int n_in,
                              void* d_out, int out_size, void* d_ws, size_t ws_size,
                              hipStream_t stream)
{
  const float* x      = (const float*)d_in[0];
  const float* w_qkv  = (const float*)d_in[1];
  const float* b_qkv  = (const float*)d_in[2];
  const float* w_o    = (const float*)d_in[3];
  const float* b_o    = (const float*)d_in[4];
  float* out = (float*)d_out;

  unsigned short* xb    = (unsigned short*)d_ws;          // 4096x768
  unsigned short* wqkvb = xb    + (size_t)M_ * K_;        // 2304x768
  unsigned short* wob   = wqkvb + (size_t)N_QKV * K_;     // 768x768
  unsigned short* Qw    = wob   + (size_t)H_ * H_;        // (b,h,s,d)
  unsigned short* Kw    = Qw + (size_t)QKV_ELEMS;         // (b,h,s,d)
  unsigned short* Vtw   = Kw + (size_t)QKV_ELEMS;         // (b,h,d,s)  TRANSPOSED
  unsigned short* attn  = Vtw + (size_t)QKV_ELEMS;        // 4096x768

  cast3<<<5376, 256, 0, stream>>>(x, xb, 786432,
                                  w_qkv, wqkvb, 442368,
                                  w_o, wob, 147456);
  gemm_nt<N_QKV, 0><<<dim3(18, 32), 256, 0, stream>>>(xb, wqkvb, b_qkv, Qw, nullptr);
  attn_fwd<<<dim3(768), 256, 0, stream>>>(Qw, Kw, Vtw, attn);
  gemm_nt<H_, 1><<<dim3(6, 32), 256, 0, stream>>>(attn, wob, b_o, nullptr, out);
}